// Round 12
// baseline (762.953 us; speedup 1.0000x reference)
//
#include <hip/hip_runtime.h>
#include <hip/hip_bf16.h>
#include <math.h>

// V2TransformerLayer: B=4, T=2048, D=1024, H=16, Dh=64, FF=4096
#define TT   2048
#define DD   1024
#define HHD  16
#define FFD  4096
#define NTOK 8192

typedef __attribute__((ext_vector_type(8))) short bf16x8;
typedef __attribute__((ext_vector_type(4))) float f32x4;
typedef unsigned int u32;
#define AS(n) __attribute__((address_space(n)))

__device__ __forceinline__ unsigned short f2bf(float f) {
    u32 u = __builtin_bit_cast(u32, f);
    u += 0x7fffu + ((u >> 16) & 1u);
    return (unsigned short)(u >> 16);
}

__device__ __forceinline__ void gld_lds16(const void* g, void* l) {
    __builtin_amdgcn_global_load_lds((const AS(1) u32*)g, (AS(3) u32*)l, 16, 0, 0);
}

__device__ __forceinline__ int swz(int row) { return (row + (row >> 3)) & 7; }

// ---------------------------------------------------------------------------
// Weight transpose + cast: W[K][N] fp32 -> Wt[N][K] bf16
// ---------------------------------------------------------------------------
__global__ __launch_bounds__(256) void wtrans(const float* __restrict__ W,
                                              unsigned short* __restrict__ Wt,
                                              int K, int N) {
    __shared__ float t[32][33];
    int tx = threadIdx.x & 31, ty = threadIdx.x >> 5;
    int n0 = blockIdx.x * 32, k0 = blockIdx.y * 32;
    #pragma unroll
    for (int i = 0; i < 32; i += 8)
        t[ty + i][tx] = W[(size_t)(k0 + ty + i) * N + n0 + tx];
    __syncthreads();
    #pragma unroll
    for (int i = 0; i < 32; i += 8)
        Wt[(size_t)(n0 + ty + i) * K + k0 + tx] = f2bf(t[tx][ty + i]);
}

// ---------------------------------------------------------------------------
// LayerNorm fp32 in -> bf16 out.
// ---------------------------------------------------------------------------
__global__ __launch_bounds__(256) void ln_bf16(const float* __restrict__ x,
                                               const float* __restrict__ g,
                                               const float* __restrict__ be,
                                               unsigned short* __restrict__ y) {
    int tok = blockIdx.x, tid = threadIdx.x;
    float4 v = ((const float4*)(x + (size_t)tok * DD))[tid];
    float s  = v.x + v.y + v.z + v.w;
    float ss = v.x*v.x + v.y*v.y + v.z*v.z + v.w*v.w;
    #pragma unroll
    for (int m = 32; m >= 1; m >>= 1) { s += __shfl_xor(s, m); ss += __shfl_xor(ss, m); }
    __shared__ float red[8];
    if ((tid & 63) == 0) { red[tid >> 6] = s; red[4 + (tid >> 6)] = ss; }
    __syncthreads();
    s  = red[0] + red[1] + red[2] + red[3];
    ss = red[4] + red[5] + red[6] + red[7];
    float mu   = s * (1.0f / DD);
    float rstd = rsqrtf(ss * (1.0f / DD) - mu * mu + 1e-5f);
    float4 gv = ((const float4*)g)[tid];
    float4 bv = ((const float4*)be)[tid];
    ushort4 o;
    o.x = f2bf((v.x - mu) * rstd * gv.x + bv.x);
    o.y = f2bf((v.y - mu) * rstd * gv.y + bv.y);
    o.z = f2bf((v.z - mu) * rstd * gv.z + bv.z);
    o.w = f2bf((v.w - mu) * rstd * gv.w + bv.w);
    *(ushort4*)(y + (size_t)tok * DD + tid * 4) = o;
}

// ---------------------------------------------------------------------------
// 8-wave 256x128 bf16 MFMA GEMM, 4-phase K-loop with counted vmcnt (T3+T4+T5).
// C[M,N] = A[M,K] @ Bt[N,K]^T + bias.  BK=64, double-buffered LDS (96KB).
// Per-wave 64x64 output (4x4 frags of 16x16x32) — fragment math identical to
// the round-7/11 verified kernel; only the loop skeleton is new.
// vmcnt(2) once per tile (2 next-tile loads in flight), lgkmcnt(0) at phase 3
// retires all ds_reads before any wave's next-tile gld_lds can overwrite.
// MODE 1: scatter bf16 (B,H,T,Dh), val *= oscale   MODE 2: fp32 + resid
// MODE 3: GELU bf16                                 MODE 4: scatter bf16 (B,H,Dh,T), bias/row
// ---------------------------------------------------------------------------
template <int MODE>
__global__ __launch_bounds__(512, 2) void gemm8(const unsigned short* __restrict__ A,
                                                const unsigned short* __restrict__ Bt,
                                                const float* __restrict__ bias,
                                                void* __restrict__ C,
                                                const float* __restrict__ resid,
                                                float oscale, int M, int N, int K) {
    __shared__ __align__(16) unsigned short As[2][256 * 64];
    __shared__ __align__(16) unsigned short Bs[2][128 * 64];
    int tid = threadIdx.x, lane = tid & 63, w = tid >> 6;   // 8 waves
    int wm = w >> 1, wn = w & 1;                            // 4M x 2N
    int m0 = blockIdx.y * 256, n0 = blockIdx.x * 128;
    int c = lane & 15, g = lane >> 4;

    f32x4 acc[4][4];
    f32x4 z4 = {0.f, 0.f, 0.f, 0.f};
    #pragma unroll
    for (int i = 0; i < 4; ++i)
        #pragma unroll
        for (int j = 0; j < 4; ++j) acc[i][j] = z4;

    // staging descriptors: A 32KB = 4 insts/wave, B 16KB = 2 insts/wave
    const unsigned short* aSrc[4]; int aOff[4];
    const unsigned short* bSrc[2]; int bOff[2];
    #pragma unroll
    for (int i = 0; i < 4; ++i) {
        int inst = w * 4 + i;
        int row  = inst * 8 + (lane >> 3);
        int kk   = ((lane & 7) ^ swz(row)) << 3;
        aSrc[i] = A + (size_t)(m0 + row) * K + kk;
        aOff[i] = inst * 1024;
    }
    #pragma unroll
    for (int j = 0; j < 2; ++j) {
        int inst = w * 2 + j;
        int row  = inst * 8 + (lane >> 3);
        int kk   = ((lane & 7) ^ swz(row)) << 3;
        bSrc[j] = Bt + (size_t)(n0 + row) * K + kk;
        bOff[j] = inst * 1024;
    }

    // prologue: stage tile 0 -> buf 0  (6 loads in flight per wave)
    #pragma unroll
    for (int i = 0; i < 4; ++i) gld_lds16(aSrc[i], (char*)As[0] + aOff[i]);
    #pragma unroll
    for (int j = 0; j < 2; ++j) gld_lds16(bSrc[j], (char*)Bs[0] + bOff[j]);

    int NK = K >> 6;
    for (int kt = 0; kt < NK; ++kt) {
        int cur = kt & 1, nxt = cur ^ 1;
        bool pre = (kt + 1 < NK);
        int k1 = (kt + 1) << 6;
        const char* Ab = (const char*)As[cur];
        const char* Bb = (const char*)Bs[cur];
        char* An = (char*)As[nxt];
        char* Bn = (char*)Bs[nxt];
        bf16x8 br[4], a0, a1, a2, a3;

        // ---- phase 0: stage A01(next); validate tile; rows 0,1 @ ks=0
        if (pre) {
            gld_lds16(aSrc[0] + k1, An + aOff[0]);
            gld_lds16(aSrc[1] + k1, An + aOff[1]);
            asm volatile("s_waitcnt vmcnt(2)" ::: "memory");
        } else {
            asm volatile("s_waitcnt vmcnt(0)" ::: "memory");
        }
        __builtin_amdgcn_sched_barrier(0);
        asm volatile("s_barrier" ::: "memory");
        #pragma unroll
        for (int f = 0; f < 4; ++f) {
            int rb = wn * 64 + f * 16 + c;
            br[f] = *(const bf16x8*)(Bb + rb * 128 + ((g ^ swz(rb)) << 4));
        }
        { int ra = wm * 64 + c;      a0 = *(const bf16x8*)(Ab + ra * 128 + ((g ^ swz(ra)) << 4)); }
        { int ra = wm * 64 + 16 + c; a1 = *(const bf16x8*)(Ab + ra * 128 + ((g ^ swz(ra)) << 4)); }
        asm volatile("s_barrier" ::: "memory");
        __builtin_amdgcn_s_setprio(1);
        #pragma unroll
        for (int j = 0; j < 4; ++j) acc[0][j] = __builtin_amdgcn_mfma_f32_16x16x32_bf16(a0, br[j], acc[0][j], 0, 0, 0);
        #pragma unroll
        for (int j = 0; j < 4; ++j) acc[1][j] = __builtin_amdgcn_mfma_f32_16x16x32_bf16(a1, br[j], acc[1][j], 0, 0, 0);
        __builtin_amdgcn_s_setprio(0);

        // ---- phase 1: stage A23(next); rows 2,3 @ ks=0
        if (pre) {
            gld_lds16(aSrc[2] + k1, An + aOff[2]);
            gld_lds16(aSrc[3] + k1, An + aOff[3]);
        }
        { int ra = wm * 64 + 32 + c; a2 = *(const bf16x8*)(Ab + ra * 128 + ((g ^ swz(ra)) << 4)); }
        { int ra = wm * 64 + 48 + c; a3 = *(const bf16x8*)(Ab + ra * 128 + ((g ^ swz(ra)) << 4)); }
        asm volatile("s_barrier" ::: "memory");
        __builtin_amdgcn_s_setprio(1);
        #pragma unroll
        for (int j = 0; j < 4; ++j) acc[2][j] = __builtin_amdgcn_mfma_f32_16x16x32_bf16(a2, br[j], acc[2][j], 0, 0, 0);
        #pragma unroll
        for (int j = 0; j < 4; ++j) acc[3][j] = __builtin_amdgcn_mfma_f32_16x16x32_bf16(a3, br[j], acc[3][j], 0, 0, 0);
        __builtin_amdgcn_s_setprio(0);

        // ---- phase 2: stage B01(next); rows 0,1 @ ks=1
        if (pre) {
            gld_lds16(bSrc[0] + k1, Bn + bOff[0]);
            gld_lds16(bSrc[1] + k1, Bn + bOff[1]);
        }
        #pragma unroll
        for (int f = 0; f < 4; ++f) {
            int rb = wn * 64 + f * 16 + c;
            br[f] = *(const bf16x8*)(Bb + rb * 128 + (((4 + g) ^ swz(rb)) << 4));
        }
        { int ra = wm * 64 + c;      a0 = *(const bf16x8*)(Ab + ra * 128 + (((4 + g) ^ swz(ra)) << 4)); }
        { int ra = wm * 64 + 16 + c; a1 = *(const bf16x8*)(Ab + ra * 128 + (((4 + g) ^ swz(ra)) << 4)); }
        asm volatile("s_barrier" ::: "memory");
        __builtin_amdgcn_s_setprio(1);
        #pragma unroll
        for (int j = 0; j < 4; ++j) acc[0][j] = __builtin_amdgcn_mfma_f32_16x16x32_bf16(a0, br[j], acc[0][j], 0, 0, 0);
        #pragma unroll
        for (int j = 0; j < 4; ++j) acc[1][j] = __builtin_amdgcn_mfma_f32_16x16x32_bf16(a1, br[j], acc[1][j], 0, 0, 0);
        __builtin_amdgcn_s_setprio(0);

        // ---- phase 3: rows 2,3 @ ks=1; drain lgkm so next-tile glds can't clobber
        { int ra = wm * 64 + 32 + c; a2 = *(const bf16x8*)(Ab + ra * 128 + (((4 + g) ^ swz(ra)) << 4)); }
        { int ra = wm * 64 + 48 + c; a3 = *(const bf16x8*)(Ab + ra * 128 + (((4 + g) ^ swz(ra)) << 4)); }
        asm volatile("s_waitcnt lgkmcnt(0)" ::: "memory");
        __builtin_amdgcn_sched_barrier(0);
        asm volatile("s_barrier" ::: "memory");
        __builtin_amdgcn_s_setprio(1);
        #pragma unroll
        for (int j = 0; j < 4; ++j) acc[2][j] = __builtin_amdgcn_mfma_f32_16x16x32_bf16(a2, br[j], acc[2][j], 0, 0, 0);
        #pragma unroll
        for (int j = 0; j < 4; ++j) acc[3][j] = __builtin_amdgcn_mfma_f32_16x16x32_bf16(a3, br[j], acc[3][j], 0, 0, 0);
        __builtin_amdgcn_s_setprio(0);
    }

    // epilogue
    float bcol[4];
    float4 brow[4];
    if (MODE == 4) {
        #pragma unroll
        for (int i = 0; i < 4; ++i)
            brow[i] = *(const float4*)&bias[m0 + wm * 64 + i * 16 + g * 4];
    } else {
        #pragma unroll
        for (int j = 0; j < 4; ++j) bcol[j] = bias[n0 + wn * 64 + j * 16 + c];
    }
    #pragma unroll
    for (int i = 0; i < 4; ++i) {
        #pragma unroll
        for (int r = 0; r < 4; ++r) {
            int rowm = m0 + wm * 64 + i * 16 + g * 4 + r;
            float br_ = (MODE == 4) ? ((const float*)&brow[i])[r] : 0.0f;
            #pragma unroll
            for (int j = 0; j < 4; ++j) {
                float val = acc[i][j][r] + ((MODE == 4) ? br_ : bcol[j]);
                int col = n0 + wn * 64 + j * 16 + c;
                if (MODE == 1) {
                    val *= oscale;
                    int b = rowm >> 11, t = rowm & 2047, h = col >> 6, d = col & 63;
                    ((unsigned short*)C)[(((size_t)((b << 4) + h) * TT + t) << 6) + d] = f2bf(val);
                } else if (MODE == 2) {
                    size_t idx = (size_t)rowm * N + col;
                    ((float*)C)[idx] = val + resid[idx];
                } else if (MODE == 3) {
                    float ge = 0.5f * val * (1.0f + erff(val * 0.70710678118f));
                    ((unsigned short*)C)[(size_t)rowm * N + col] = f2bf(ge);
                } else {
                    int b = col >> 11, t = col & 2047, h = rowm >> 6, d = rowm & 63;
                    ((unsigned short*)C)[(((size_t)((b << 4) + h) * 64 + d) << 11) + t] = f2bf(val);
                }
            }
        }
    }
}

// ---------------------------------------------------------------------------
// bf16 flash attention, causal. Pair-balanced {p,31-p}, 1024 blocks = 4/CU.
// Q pre-scaled by 0.125*log2(e) at projection -> softmax in exp2 space.
// Causal mask only on the (wave-uniform) diagonal tile.
// ---------------------------------------------------------------------------
__global__ __launch_bounds__(256, 4) void attn_bf16(const unsigned short* __restrict__ q,
                                                    const unsigned short* __restrict__ k,
                                                    const unsigned short* __restrict__ vt,
                                                    unsigned short* __restrict__ ao) {
    __shared__ __align__(16) unsigned short Ks[2][64 * 64];
    __shared__ __align__(16) unsigned short Vts[2][64 * 64];
    __shared__ __align__(16) unsigned short Ps[4][16 * 64];
    int tid = threadIdx.x, lane = tid & 63, w = tid >> 6;
    int bid = blockIdx.x;
    int bh  = (bid & 7) * 8 + ((bid >> 3) & 7);
    int pr  = bid >> 6;
    int c = lane & 15, g = lane >> 4;
    size_t kbase = (size_t)bh * TT * 64;
    size_t vbase = (size_t)bh * 64 * TT;

    const unsigned short* kSrc[2];
    const unsigned short* vSrc[2];
    int ldsOff[2];
    #pragma unroll
    for (int i = 0; i < 2; ++i) {
        int inst = w * 2 + i;
        int row  = inst * 8 + (lane >> 3);
        int kk   = ((lane & 7) ^ swz(row)) << 3;
        kSrc[i] = k  + kbase + (size_t)row * 64 + kk;
        vSrc[i] = vt + vbase + (size_t)row * TT + kk;
        ldsOff[i] = inst * 1024;
    }

    auto STAGE = [&](int buf, int kv0) {
        #pragma unroll
        for (int i = 0; i < 2; ++i) {
            gld_lds16(kSrc[i] + (size_t)kv0 * 64, (char*)Ks[buf] + ldsOff[i]);
            gld_lds16(vSrc[i] + kv0,              (char*)Vts[buf] + ldsOff[i]);
        }
    };

    int b = bh >> 4, h = bh & 15;
    f32x4 z4 = {0.f, 0.f, 0.f, 0.f};

    for (int ph = 0; ph < 2; ++ph) {
        int qt = ph ? (31 - pr) : pr;
        int q0 = qt * 64;
        int qrow = q0 + w * 16 + c;
        bf16x8 qf[2];
        qf[0] = *(const bf16x8*)(q + kbase + (size_t)qrow * 64 + g * 8);
        qf[1] = *(const bf16x8*)(q + kbase + (size_t)qrow * 64 + 32 + g * 8);

        float m_i[4], l_i[4];
        f32x4 o[4];
        #pragma unroll
        for (int j = 0; j < 4; ++j) { m_i[j] = -INFINITY; l_i[j] = 0.0f; o[j] = z4; }

        __syncthreads();
        STAGE(0, 0);

        for (int kt = 0; kt <= qt; ++kt) {
            int cur = kt & 1, kv0 = kt * 64;
            __syncthreads();
            if (kt < qt) STAGE(cur ^ 1, kv0 + 64);

            // S = Q @ K^T  (exp2-scaled space)
            f32x4 s[4];
            #pragma unroll
            for (int f = 0; f < 4; ++f) s[f] = z4;
            __builtin_amdgcn_s_setprio(1);
            #pragma unroll
            for (int ks = 0; ks < 2; ++ks) {
                int slot = ks * 4 + g;
                #pragma unroll
                for (int f = 0; f < 4; ++f) {
                    int rb = f * 16 + c;
                    bf16x8 kf = *(const bf16x8*)((const char*)Ks[cur] + rb * 128 + ((slot ^ swz(rb)) << 4));
                    s[f] = __builtin_amdgcn_mfma_f32_16x16x32_bf16(qf[ks], kf, s[f], 0, 0, 0);
                }
            }
            __builtin_amdgcn_s_setprio(0);

            bool diag = (kt == qt);
            #pragma unroll
            for (int j = 0; j < 4; ++j) {
                int lq = g * 4 + j;
                int gq = q0 + w * 16 + lq;
                if (diag) {
                    #pragma unroll
                    for (int f = 0; f < 4; ++f)
                        if (kv0 + f * 16 + c > gq) s[f][j] = -INFINITY;
                }
                float mx = fmaxf(fmaxf(s[0][j], s[1][j]), fmaxf(s[2][j], s[3][j]));
                #pragma unroll
                for (int mm = 8; mm >= 1; mm >>= 1) mx = fmaxf(mx, __shfl_xor(mx, mm));
                float newm = fmaxf(m_i[j], mx);
                float al = exp2f(m_i[j] - newm);
                float rs = 0.0f;
                #pragma unroll
                for (int f = 0; f < 4; ++f) {
                    float p = exp2f(s[f][j] - newm);
                    s[f][j] = p;
                    rs += p;
                }
                #pragma unroll
                for (int mm = 8; mm >= 1; mm >>= 1) rs += __shfl_xor(rs, mm);
                l_i[j] = l_i[j] * al + rs;
                m_i[j] = newm;
                #pragma unroll
                for (int f = 0; f < 4; ++f) {
                    int col = f * 16 + c;
                    int byte = lq * 128 + (((col >> 3) ^ swz(lq)) << 4) + ((col & 7) << 1);
                    *(unsigned short*)((char*)Ps[w] + byte) = f2bf(s[f][j]);
                }
                #pragma unroll
                for (int fd = 0; fd < 4; ++fd) o[fd][j] *= al;
            }
            asm volatile("s_waitcnt lgkmcnt(0)" ::: "memory");
            __builtin_amdgcn_sched_barrier(0);

            // O += P @ V
            __builtin_amdgcn_s_setprio(1);
            #pragma unroll
            for (int ks = 0; ks < 2; ++ks) {
                int slot = ks * 4 + g;
                bf16x8 pa = *(const bf16x8*)((const char*)Ps[w] + c * 128 + ((slot ^ swz(c)) << 4));
                #pragma unroll
                for (int fd = 0; fd < 4; ++fd) {
                    int rv = fd * 16 + c;
                    bf16x8 vf = *(const bf16x8*)((const char*)Vts[cur] + rv * 128 + ((slot ^ swz(rv)) << 4));
                    o[fd] = __builtin_amdgcn_mfma_f32_16x16x32_bf16(pa, vf, o[fd], 0, 0, 0);
                }
            }
            __builtin_amdgcn_s_setprio(0);
        }

        #pragma unroll
        for (int fd = 0; fd < 4; ++fd)
            #pragma unroll
            for (int j = 0; j < 4; ++j) {
                int t = q0 + w * 16 + g * 4 + j;
                float val = o[fd][j] / l_i[j];
                ao[(((size_t)(b * TT + t)) << 10) + (h << 6) + fd * 16 + c] = f2bf(val);
            }
    }
}

// ---------------------------------------------------------------------------
// Launch. ws: [0,16M) xn | [16,32M) q | [32,48M) k | [48,64M) v^T |
// [64,80M) ao | [80,104M) Wt's.  h1 (64MB) reuses q..ao. x2 = d_out (fp32).
// ---------------------------------------------------------------------------
extern "C" void kernel_launch(void* const* d_in, const int* in_sizes, int n_in,
                              void* d_out, int out_size, void* d_ws, size_t ws_size,
                              hipStream_t stream) {
    const float* x   = (const float*)d_in[0];
    const float* Wq  = (const float*)d_in[2];
    const float* bq  = (const float*)d_in[3];
    const float* Wk  = (const float*)d_in[4];
    const float* bk  = (const float*)d_in[5];
    const float* Wv  = (const float*)d_in[6];
    const float* bv  = (const float*)d_in[7];
    const float* Wo  = (const float*)d_in[8];
    const float* bo  = (const float*)d_in[9];
    const float* W1  = (const float*)d_in[10];
    const float* b1  = (const float*)d_in[11];
    const float* W2  = (const float*)d_in[12];
    const float* b2  = (const float*)d_in[13];
    const float* g1  = (const float*)d_in[14];
    const float* be1 = (const float*)d_in[15];
    const float* g2  = (const float*)d_in[16];
    const float* be2 = (const float*)d_in[17];

    float* out = (float*)d_out;
    char* w = (char*)d_ws;
    const size_t MB = 1024 * 1024;
    unsigned short* xnb = (unsigned short*)(w);
    unsigned short* qb  = (unsigned short*)(w + 16 * MB);
    unsigned short* kb  = (unsigned short*)(w + 32 * MB);
    unsigned short* vb  = (unsigned short*)(w + 48 * MB);   // V^T [bh][d][t]
    unsigned short* aob = (unsigned short*)(w + 64 * MB);
    unsigned short* wqt = (unsigned short*)(w + 80 * MB);
    unsigned short* wkt = wqt + 1 * MB;
    unsigned short* wvt = wqt + 2 * MB;
    unsigned short* wot = wqt + 3 * MB;
    unsigned short* w1t = wqt + 4 * MB;
    unsigned short* w2t = w1t + 4 * MB;
    unsigned short* h1  = qb;

    dim3 blk(256);
    wtrans<<<dim3(DD / 32, DD / 32), blk, 0, stream>>>(Wq, wqt, DD, DD);
    wtrans<<<dim3(DD / 32, DD / 32), blk, 0, stream>>>(Wk, wkt, DD, DD);
    wtrans<<<dim3(DD / 32, DD / 32), blk, 0, stream>>>(Wv, wvt, DD, DD);
    wtrans<<<dim3(DD / 32, DD / 32), blk, 0, stream>>>(Wo, wot, DD, DD);
    wtrans<<<dim3(FFD / 32, DD / 32), blk, 0, stream>>>(W1, w1t, DD, FFD);
    wtrans<<<dim3(DD / 32, FFD / 32), blk, 0, stream>>>(W2, w2t, FFD, DD);

    ln_bf16<<<NTOK, blk, 0, stream>>>(x, g1, be1, xnb);

    dim3 blk8(512);
    const float QSCALE = 0.18033688011112042f;   // 0.125 * log2(e)
    dim3 gD(DD / 128, NTOK / 256);    // (8, 32)
    dim3 gF(FFD / 128, NTOK / 256);   // (32, 32)
    dim3 gV(NTOK / 128, DD / 256);    // (64, 4)
    gemm8<1><<<gD, blk8, 0, stream>>>(xnb, wqt, bq, qb, nullptr, QSCALE, NTOK, DD, DD);
    gemm8<1><<<gD, blk8, 0, stream>>>(xnb, wkt, bk, kb, nullptr, 1.0f, NTOK, DD, DD);
    gemm8<4><<<gV, blk8, 0, stream>>>(wvt, xnb, bv, vb, nullptr, 1.0f, DD, NTOK, DD);

    attn_bf16<<<dim3(1024), blk, 0, stream>>>(qb, kb, vb, aob);

    gemm8<2><<<gD, blk8, 0, stream>>>(aob, wot, bo, out, x, 1.0f, NTOK, DD, DD);
    ln_bf16<<<NTOK, blk, 0, stream>>>(out, g2, be2, xnb);
    gemm8<3><<<gF, blk8, 0, stream>>>(xnb, w1t, b1, h1, nullptr, 1.0f, NTOK, FFD, DD);
    gemm8<2><<<gD, blk8, 0, stream>>>(h1, w2t, b2, out, out, 1.0f, NTOK, DD, FFD);
}